// Round 14
// baseline (394.018 us; speedup 1.0000x reference)
//
#include <hip/hip_runtime.h>
#include <cstdint>

#define NN 4
#define CC 64
#define VV 25
#define TT 300
#define MM 2
#define HH 8
#define HD 32
#define EE 256

typedef short bf16x8 __attribute__((ext_vector_type(8)));
typedef float f32x4 __attribute__((ext_vector_type(4)));
typedef float f32x2 __attribute__((ext_vector_type(2)));
typedef unsigned int u32x4 __attribute__((ext_vector_type(4)));

__device__ __forceinline__ unsigned short f2bf(float f) {
  union { float f; unsigned u; } x; x.f = f;
  unsigned r = x.u + 0x7FFF + ((x.u >> 16) & 1);  // RNE
  return (unsigned short)(r >> 16);
}
__device__ __forceinline__ float bf2f(unsigned short s) {
  union { unsigned u; float f; } x; x.u = ((unsigned)s) << 16;
  return x.f;
}
// truncation split: hi = upper 16 bits (1 op vs 4 for RNE). Pair precision
// unchanged: |lo| <= 2^-8|s| (vs 2^-9), lo's RNE error <= 2^-17|s| either way.
__device__ __forceinline__ unsigned short truncbf(float f) {
  union { float f; unsigned u; } x; x.f = f;
  return (unsigned short)(x.u >> 16);
}
__device__ __forceinline__ float bperm(int byteaddr, float v) {
  return __int_as_float(__builtin_amdgcn_ds_bpermute(byteaddr, __float_as_int(v)));
}
// unpack 8 packed u32 (hi16|lo16 per element) -> hi bf16x8 + lo bf16x8.
// Value-verified in R10/R12 (passed correctness); register-only bitcasts.
__device__ __forceinline__ void unpack8(u32x4 a, u32x4 b, bf16x8& H8, bf16x8& L8) {
  union { unsigned u[4]; bf16x8 v; } H, L;
  H.u[0] = (a[1] & 0xFFFF0000u) | (a[0] >> 16);
  H.u[1] = (a[3] & 0xFFFF0000u) | (a[2] >> 16);
  H.u[2] = (b[1] & 0xFFFF0000u) | (b[0] >> 16);
  H.u[3] = (b[3] & 0xFFFF0000u) | (b[2] >> 16);
  L.u[0] = (a[1] << 16) | (a[0] & 0xFFFFu);
  L.u[1] = (a[3] << 16) | (a[2] & 0xFFFFu);
  L.u[2] = (b[1] << 16) | (b[0] & 0xFFFFu);
  L.u[3] = (b[3] << 16) | (b[2] & 0xFFFFu);
  H8 = H.v; L8 = L.v;
}

// ws layout:
//   Qp : u32 [b,v,h,t<300,d] packed (hi16|lo16), 15.36M u32 (old Qh+Ql span)
//   Kh,Kl : ushort [b,v,h,t<300,d] (15.36M each) [K x1/16]
//   Vt : ushort [b,v,h,d][t pad 320] (16,384,000)
//   (Oh/Ol regions now unused -- merge fused into attn)
//   WhT,WlT [c][e]; WqTh,WqTl [e][c]; btPad [704][32]
#define QKN 15360000
#define VTN 16384000
#define LOG2E 1.4426950408889634f

// ---------------- prep: transpose/split weights + bf16 bias table ----------------
__global__ __launch_bounds__(256) void prep_kernel(
    const float* __restrict__ w_qkv, const float* __restrict__ w_merge,
    const float* __restrict__ bias_table,
    unsigned short* __restrict__ WqTh, unsigned short* __restrict__ WqTl,
    unsigned short* __restrict__ WhT, unsigned short* __restrict__ WlT,
    unsigned short* __restrict__ btPad)
{
  int i = blockIdx.x * 256 + threadIdx.x;
  if (i < 49152) {                      // w_qkv [c][768] -> [e][c] hi/lo
    int c = i / 768, e = i % 768;
    float v = w_qkv[i];
    unsigned short hb = truncbf(v);
    WqTh[e * 64 + c] = hb; WqTl[e * 64 + c] = f2bf(v - bf2f(hb));
  } else if (i < 65536) {               // w_merge [e][64] -> [c][e] hi/lo
    int j = i - 49152;
    int e = j >> 6, c = j & 63;
    float v = w_merge[j];
    unsigned short hb = truncbf(v);
    WhT[c * EE + e] = hb; WlT[c * EE + e] = f2bf(v - bf2f(hb));
  } else if (i < 65536 + 22528) {       // bias_table -> padded bf16 [704][32]
    int j = i - 65536;
    int row = j >> 5, d = j & 31;
    int g = row - 20;
    float v = (g >= 0 && g < 2 * TT - 1) ? bias_table[g * 32 + d] : 0.f;
    btPad[j] = f2bf(v);
  }
}

// ---------------- Kernel A: QKV projection via MFMA (R12-exact) ----------------
__global__ __launch_bounds__(256, 3) void qkv_kernel(
    const float* __restrict__ x, const float* __restrict__ b_qkv,
    const unsigned short* __restrict__ WqTh, const unsigned short* __restrict__ WqTl,
    unsigned* __restrict__ Qp,
    unsigned short* __restrict__ Kh, unsigned short* __restrict__ Kl,
    unsigned short* __restrict__ Vt)
{
  __shared__ __align__(16) union {
    unsigned int a[64 * 68];      // sA2[t][c] packed (hi<<16)|lo, stride 68
    unsigned short vtr[256 * 66]; // V transpose buffer [e'][t]
  } sm;

  int blk = blockIdx.x;
  int tt = blk % 5; blk /= 5;
  int v25 = blk % 25; int b = blk / 25;
  int n = b >> 1, m = b & 1;
  int t0 = tt * 60;
  int tid = threadIdx.x;
  int w = tid >> 6, lane = tid & 63, quad = lane >> 4, c16 = lane & 15;

  for (int i = tid; i < 64 * 64; i += 256) {
    int c = i >> 6, t = i & 63;
    float val = 0.f;
    if (t < 60) val = x[((((size_t)n * CC + c) * VV + v25) * TT + (t0 + t)) * MM + m];
    union { float f; unsigned u; } xb; xb.f = val;
    unsigned hi16 = xb.u & 0xFFFF0000u;
    unsigned short lb = f2bf(val - __uint_as_float(hi16));
    sm.a[t * 68 + c] = hi16 | (unsigned)lb;
  }
  __syncthreads();

  bf16x8 ah[4][2], al[4][2];
  #pragma unroll
  for (int mt = 0; mt < 4; ++mt)
    #pragma unroll
    for (int kc = 0; kc < 2; ++kc) {
      const u32x4* p = (const u32x4*)&sm.a[(mt * 16 + c16) * 68 + kc * 32 + quad * 8];
      unpack8(p[0], p[1], ah[mt][kc], al[mt][kc]);
    }
  __syncthreads();  // sA dead; sVt (union) may be written

  size_t bv = (size_t)(b * VV + v25);
  int e0w = w * 192;
  for (int nt = 0; nt < 12; ++nt) {
    int ebase = e0w + nt * 16;
    int e = ebase + c16;
    bf16x8 bh[2], bl[2];
    #pragma unroll
    for (int kc = 0; kc < 2; ++kc) {
      bh[kc] = *(const bf16x8*)&WqTh[(size_t)e * 64 + kc * 32 + quad * 8];
      bl[kc] = *(const bf16x8*)&WqTl[(size_t)e * 64 + kc * 32 + quad * 8];
    }
    f32x4 acc[4];
    #pragma unroll
    for (int mt = 0; mt < 4; ++mt) {
      acc[mt] = (f32x4){0.f, 0.f, 0.f, 0.f};
      #pragma unroll
      for (int kc = 0; kc < 2; ++kc) {
        acc[mt] = __builtin_amdgcn_mfma_f32_16x16x32_bf16(ah[mt][kc], bh[kc], acc[mt], 0, 0, 0);
        acc[mt] = __builtin_amdgcn_mfma_f32_16x16x32_bf16(al[mt][kc], bh[kc], acc[mt], 0, 0, 0);
        acc[mt] = __builtin_amdgcn_mfma_f32_16x16x32_bf16(ah[mt][kc], bl[kc], acc[mt], 0, 0, 0);
      }
    }
    float bias = b_qkv[e];
    int which = ebase >> 8;  // wave-uniform
    if (which == 0) {        // Q: packed u32 store
      int hh = (e >> 5) & 7, dd = e & 31;
      size_t rowb = (bv * HH + hh) * TT;
      #pragma unroll
      for (int mt = 0; mt < 4; ++mt)
        #pragma unroll
        for (int reg = 0; reg < 4; ++reg) {
          int lrow = mt * 16 + quad * 4 + reg;
          // rows >= 60 would RACE with the next tt-block (zero-staged x)
          if (lrow < 60) {
            int t = t0 + lrow;
            float s = (acc[mt][reg] + bias) * LOG2E;
            union { float f; unsigned u; } sb; sb.f = s;
            unsigned hi16 = sb.u & 0xFFFF0000u;
            unsigned short lb2 = f2bf(s - __uint_as_float(hi16));
            Qp[(rowb + t) * HD + dd] = hi16 | (unsigned)lb2;
          }
        }
    } else if (which == 1) { // K: unpacked hi/lo stores
      int hh = (e >> 5) & 7, dd = e & 31;
      size_t rowb = (bv * HH + hh) * TT;
      #pragma unroll
      for (int mt = 0; mt < 4; ++mt)
        #pragma unroll
        for (int reg = 0; reg < 4; ++reg) {
          int lrow = mt * 16 + quad * 4 + reg;
          if (lrow < 60) {
            int t = t0 + lrow;
            float s = (acc[mt][reg] + bias) * 0.0625f;
            unsigned short hb = truncbf(s);
            size_t idx = (rowb + t) * HD + dd;
            Kh[idx] = hb; Kl[idx] = f2bf(s - bf2f(hb));
          }
        }
    } else {
      int ep = e - 512;
      #pragma unroll
      for (int mt = 0; mt < 4; ++mt)
        #pragma unroll
        for (int reg = 0; reg < 4; ++reg)
          sm.vtr[ep * 66 + mt * 16 + quad * 4 + reg] = f2bf(acc[mt][reg] + bias);
    }
  }
  __syncthreads();
  for (int i = tid; i < 256 * 30; i += 256) {
    int ep = i / 30, tc = (i % 30) * 2;
    int e = 512 + ep;
    int hh = (e >> 5) & 7, dd = e & 31;
    size_t idx = ((bv * HH + hh) * HD + dd) * 320 + t0 + tc;
    *(unsigned int*)&Vt[idx] = *(const unsigned int*)&sm.vtr[ep * 66 + tc];
    // Vt rows t in [300,320) stay poison (finite bf16) -> always hit P=0.
  }
}

// ---------------- Kernel B: FUSED attention + merge ----------------
// R13: block = (b,v,lt), loops h=0..7 internally. After each head's PV:
// normalize O in-register, trunc-split to packed u32 in a wave-private LDS
// tile (same no-barrier write->read transpose pattern sPh already uses for
// P->PV), read back as MFMA A-fragments, multiply against WhT/WlT slices
// (B-frag WhT[(ct*16+c16)*256 + h*32+quad*8] -- qkv's proven [col][k]
// convention), accumulate oacc[2][4] f32 across heads. Eliminates merge4 +
// 61MB O-store + 122MB O-load. LDS 36,864 (sPh) + 16,384 (oLds) = 53,248B
// -> exactly 3 blocks/CU. Grid 600 (600%8==0, XCD swizzle bijective).
// Spill tell: WRITE_SIZE >> 15MB (kernel now writes only out ~12MB).
__global__ __launch_bounds__(256, 3) void attn_merge_kernel(
    const unsigned* __restrict__ Qp,
    const unsigned short* __restrict__ Kh, const unsigned short* __restrict__ Kl,
    const unsigned short* __restrict__ Vt, const unsigned short* __restrict__ btPad,
    const unsigned short* __restrict__ WhT, const unsigned short* __restrict__ WlT,
    const float* __restrict__ b_merge, float* __restrict__ out)
{
  __shared__ __align__(16) unsigned short sPh[2][128 * 72];  // 36,864 B, rows wave-private
  __shared__ __align__(16) unsigned oLds[4 * 32 * 32];       // 16,384 B, wave-private O tiles

  int bid0 = blockIdx.x;
  int bid = (bid0 & 7) * 75 + (bid0 >> 3);   // 600 % 8 == 0 -> bijective XCD swizzle
  int lt = bid % 3; int rest = bid / 3;
  int v = rest % 25; int b = rest / 25;      // b in [0,8)
  int l0 = lt * 128;
  int tid = threadIdx.x;
  int w = tid >> 6, lane = tid & 63, quad = lane >> 4, c16 = lane & 15;
  if (l0 + 32 * w >= TT) return;  // fully-garbage wave: no barriers, LDS wave-private

  const unsigned short* Qp16 = (const unsigned short*)Qp;

  // rt-invariant bpermute addresses + selects (per reg)
  int srcaddr[4]; bool sel[4];
  #pragma unroll
  for (int reg = 0; reg < 4; ++reg) {
    srcaddr[reg] = 4 * (quad * 16 + ((15 + 4 * quad + reg - c16) & 15));
    sel[reg] = (4 * quad + reg) > c16;   // a==4
  }

  f32x4 oacc[2][4];   // [mt][ct] -- merged output acc, lives across the h-loop
  #pragma unroll
  for (int mt = 0; mt < 2; ++mt)
    #pragma unroll
    for (int ct = 0; ct < 4; ++ct)
      oacc[mt][ct] = (f32x4){0.f, 0.f, 0.f, 0.f};

  unsigned* oL = &oLds[w * 1024];

  for (int h = 0; h < 8; ++h) {
    size_t tbase = ((size_t)(b * VV + v) * HH + h) * TT;
    size_t vbase = ((size_t)(b * VV + v) * HH + h) * HD;

    bf16x8 qh[2], qlw[2];
    #pragma unroll
    for (int mt = 0; mt < 2; ++mt) {
      size_t qo = (tbase + l0 + w * 32 + mt * 16 + c16) * HD + quad * 8;  // u32 units
      bf16x8 raw0 = *(const bf16x8*)&Qp16[qo * 2];
      bf16x8 raw1 = *(const bf16x8*)&Qp16[qo * 2 + 8];
      union { bf16x8 v; u32x4 u; } A, B;
      A.v = raw0; B.v = raw1;
      unpack8(A.u, B.u, qh[mt], qlw[mt]);
    }

    f32x4 accO[2][2];
    #pragma unroll
    for (int mt = 0; mt < 2; ++mt)
      #pragma unroll
      for (int no = 0; no < 2; ++no)
        accO[mt][no] = (f32x4){0.f, 0.f, 0.f, 0.f};
    float psum[2][4] = {{0.f, 0.f, 0.f, 0.f}, {0.f, 0.f, 0.f, 0.f}};

    #pragma unroll
    for (int rt = 0; rt < 5; ++rt) {
      const int r0 = rt * 64;
      unsigned short* myP = &sPh[rt & 1][32 * w * 72];

      const unsigned short* kb = &Kh[(tbase + r0 + c16) * HD + quad * 8];
      const unsigned short* lb = &Kl[(tbase + r0 + c16) * HD + quad * 8];
      bf16x8 khv[4], klv[4];
      #pragma unroll
      for (int nt = 0; nt < 4; ++nt) {
        khv[nt] = *(const bf16x8*)&kb[nt * 16 * HD];
        klv[nt] = *(const bf16x8*)&lb[nt * 16 * HD];
      }
      bf16x8 vv[2][2];
      if (rt > 0) {
        int p0 = r0 - 64;  // previous tile's base
        #pragma unroll
        for (int kc = 0; kc < 2; ++kc)
          #pragma unroll
          for (int no = 0; no < 2; ++no)
            vv[kc][no] = *(const bf16x8*)&Vt[(vbase + no * 16 + c16) * 320 + p0 + kc * 32 + quad * 8];
      }
      const unsigned short* btb = &btPad[(size_t)(l0 + 256 + 32 * w - r0 + c16) * HD + quad * 8];
      bf16x8 bt6[6];
      #pragma unroll
      for (int j = 0; j < 6; ++j) bt6[j] = *(const bf16x8*)&btb[j * 16 * HD];

      #pragma unroll
      for (int mt = 0; mt < 2; ++mt) {
        float BA[4], BB[4], BC[4] = {0.f, 0.f, 0.f, 0.f};
        {
          f32x4 r = {0.f, 0.f, 0.f, 0.f};
          r = __builtin_amdgcn_mfma_f32_16x16x32_bf16(qh[mt], bt6[mt + 4], r, 0, 0, 0);
          f32x4 r2 = {0.f, 0.f, 0.f, 0.f};
          r2 = __builtin_amdgcn_mfma_f32_16x16x32_bf16(qh[mt], bt6[mt + 3], r2, 0, 0, 0);
          #pragma unroll
          for (int reg = 0; reg < 4; ++reg) BA[reg] = bperm(srcaddr[reg], r[reg]);
          #pragma unroll
          for (int reg = 0; reg < 4; ++reg) BB[reg] = bperm(srcaddr[reg], r2[reg]);
        }
        #pragma unroll
        for (int nt = 0; nt < 4; ++nt) {
          f32x4 sc = {0.f, 0.f, 0.f, 0.f};
          sc = __builtin_amdgcn_mfma_f32_16x16x32_bf16(qh[mt],  khv[nt], sc, 0, 0, 0);
          sc = __builtin_amdgcn_mfma_f32_16x16x32_bf16(qlw[mt], khv[nt], sc, 0, 0, 0);
          sc = __builtin_amdgcn_mfma_f32_16x16x32_bf16(qh[mt],  klv[nt], sc, 0, 0, 0);
          if (nt < 3) {
            f32x4 r = {0.f, 0.f, 0.f, 0.f};
            r = __builtin_amdgcn_mfma_f32_16x16x32_bf16(qh[mt], bt6[mt + 2 - nt], r, 0, 0, 0);
            #pragma unroll
            for (int reg = 0; reg < 4; ++reg) BC[reg] = bperm(srcaddr[reg], r[reg]);
          }

          bool bad = (r0 + nt * 16 + c16) >= TT;
          #pragma unroll
          for (int reg = 0; reg < 4; ++reg) {
            float ri = sel[reg] ? BA[reg] : BB[reg];
            float p = bad ? 0.f : __builtin_amdgcn_exp2f(sc[reg] + ri);
            psum[mt][reg] += p;
            myP[(mt * 16 + 4 * quad + reg) * 72 + nt * 16 + c16] = f2bf(p);
          }
          #pragma unroll
          for (int reg = 0; reg < 4; ++reg) { BA[reg] = BB[reg]; BB[reg] = BC[reg]; }
        }
      }

      if (rt > 0) {
        unsigned short* prevP = &sPh[(rt - 1) & 1][32 * w * 72];
        #pragma unroll
        for (int mt = 0; mt < 2; ++mt)
          #pragma unroll
          for (int kc = 0; kc < 2; ++kc) {
            bf16x8 pf = *(const bf16x8*)&prevP[(mt * 16 + c16) * 72 + kc * 32 + quad * 8];
            #pragma unroll
            for (int no = 0; no < 2; ++no)
              accO[mt][no] = __builtin_amdgcn_mfma_f32_16x16x32_bf16(pf, vv[kc][no], accO[mt][no], 0, 0, 0);
          }
      }
    }
    // ---- tail PV for rt=4 (buffer 0) ----
    {
      int p0 = 4 * 64;
      unsigned short* prevP = &sPh[0][32 * w * 72];
      #pragma unroll
      for (int kc = 0; kc < 2; ++kc) {
        bf16x8 vfr[2];
        #pragma unroll
        for (int no = 0; no < 2; ++no)
          vfr[no] = *(const bf16x8*)&Vt[(vbase + no * 16 + c16) * 320 + p0 + kc * 32 + quad * 8];
        #pragma unroll
        for (int mt = 0; mt < 2; ++mt) {
          bf16x8 pf = *(const bf16x8*)&prevP[(mt * 16 + c16) * 72 + kc * 32 + quad * 8];
          #pragma unroll
          for (int no = 0; no < 2; ++no)
            accO[mt][no] = __builtin_amdgcn_mfma_f32_16x16x32_bf16(pf, vfr[no], accO[mt][no], 0, 0, 0);
        }
      }
    }

    // ---- psum reduce + normalize + O->LDS transpose (wave-private, no barrier;
    //      same pattern as sPh's P write->read) ----
    #pragma unroll
    for (int mt = 0; mt < 2; ++mt)
      #pragma unroll
      for (int reg = 0; reg < 4; ++reg) {
        #pragma unroll
        for (int off = 1; off <= 8; off <<= 1)
          psum[mt][reg] += __shfl_xor(psum[mt][reg], off);
      }
    #pragma unroll
    for (int mt = 0; mt < 2; ++mt)
      #pragma unroll
      for (int no = 0; no < 2; ++no)
        #pragma unroll
        for (int reg = 0; reg < 4; ++reg) {
          float o = accO[mt][no][reg] / psum[mt][reg];
          unsigned short hb = truncbf(o);
          unsigned short lb = f2bf(o - bf2f(hb));
          oL[(mt * 16 + 4 * quad + reg) * 32 + no * 16 + c16] = ((unsigned)hb << 16) | (unsigned)lb;
        }

    // ---- merge MFMA: out[t][c] += O[t][hd] . Wm[h*32+hd][c] ----
    #pragma unroll
    for (int mt = 0; mt < 2; ++mt) {
      const u32x4* p = (const u32x4*)&oL[(mt * 16 + c16) * 32 + quad * 8];
      u32x4 a0 = p[0], a1 = p[1];
      bf16x8 oh8, ol8;
      unpack8(a0, a1, oh8, ol8);
      #pragma unroll
      for (int ct = 0; ct < 4; ++ct) {
        bf16x8 bh = *(const bf16x8*)&WhT[(size_t)(ct * 16 + c16) * EE + h * 32 + quad * 8];
        bf16x8 bl = *(const bf16x8*)&WlT[(size_t)(ct * 16 + c16) * EE + h * 32 + quad * 8];
        oacc[mt][ct] = __builtin_amdgcn_mfma_f32_16x16x32_bf16(oh8, bh, oacc[mt][ct], 0, 0, 0);
        oacc[mt][ct] = __builtin_amdgcn_mfma_f32_16x16x32_bf16(ol8, bh, oacc[mt][ct], 0, 0, 0);
        oacc[mt][ct] = __builtin_amdgcn_mfma_f32_16x16x32_bf16(oh8, bl, oacc[mt][ct], 0, 0, 0);
      }
    }
  }

  // ---- epilogue: bias + out store (out[n][c][v][t][m], n=b>>1, m=b&1) ----
  int n = b >> 1, m = b & 1;
  float bmv[4];
  #pragma unroll
  for (int ct = 0; ct < 4; ++ct) bmv[ct] = b_merge[ct * 16 + c16];
  #pragma unroll
  for (int mt = 0; mt < 2; ++mt)
    #pragma unroll
    for (int ct = 0; ct < 4; ++ct)
      #pragma unroll
      for (int reg = 0; reg < 4; ++reg) {
        int gl = l0 + 32 * w + mt * 16 + 4 * quad + reg;
        if (gl < TT) {
          int c = ct * 16 + c16;
          out[(((size_t)n * CC + c) * VV + v) * TT * MM + (size_t)gl * MM + m]
              = oacc[mt][ct][reg] + bmv[ct];
        }
      }
}

extern "C" void kernel_launch(void* const* d_in, const int* in_sizes, int n_in,
                              void* d_out, int out_size, void* d_ws, size_t ws_size,
                              hipStream_t stream) {
  const float* x          = (const float*)d_in[0];
  const float* w_qkv      = (const float*)d_in[1];
  const float* b_qkv      = (const float*)d_in[2];
  const float* w_merge    = (const float*)d_in[3];
  const float* b_merge    = (const float*)d_in[4];
  const float* bias_table = (const float*)d_in[5];
  float* out = (float*)d_out;
  unsigned short* ws16 = (unsigned short*)d_ws;
  unsigned* Qp = (unsigned*)ws16;                          // 15.36M u32 (old Qh+Ql span)
  unsigned short* Kh   = ws16 + (size_t)2 * QKN;
  unsigned short* Kl   = ws16 + (size_t)3 * QKN;
  unsigned short* Vt   = ws16 + (size_t)4 * QKN;
  unsigned short* base8 = ws16 + (size_t)6 * QKN + VTN;
  unsigned short* WhT  = base8;
  unsigned short* WlT  = base8 + 16384;
  unsigned short* WqTh = base8 + 32768;
  unsigned short* WqTl = base8 + 81920;
  unsigned short* btPad = base8 + 131072;

  prep_kernel<<<dim3(344), dim3(256), 0, stream>>>(w_qkv, w_merge, bias_table,
                                                   WqTh, WqTl, WhT, WlT, btPad);
  qkv_kernel<<<dim3(1000), dim3(256), 0, stream>>>(x, b_qkv, WqTh, WqTl,
                                                   Qp, Kh, Kl, Vt);
  attn_merge_kernel<<<dim3(600), dim3(256), 0, stream>>>(Qp, Kh, Kl, Vt, btPad,
                                                         WhT, WlT, b_merge, out);
}

// Round 15
// 295.763 us; speedup vs baseline: 1.3322x; 1.3322x over previous
//
#include <hip/hip_runtime.h>
#include <cstdint>

#define NN 4
#define CC 64
#define VV 25
#define TT 300
#define MM 2
#define HH 8
#define HD 32
#define EE 256

typedef short bf16x8 __attribute__((ext_vector_type(8)));
typedef float f32x4 __attribute__((ext_vector_type(4)));
typedef float f32x2 __attribute__((ext_vector_type(2)));
typedef unsigned int u32x4 __attribute__((ext_vector_type(4)));

__device__ __forceinline__ unsigned short f2bf(float f) {
  union { float f; unsigned u; } x; x.f = f;
  unsigned r = x.u + 0x7FFF + ((x.u >> 16) & 1);  // RNE
  return (unsigned short)(r >> 16);
}
__device__ __forceinline__ float bf2f(unsigned short s) {
  union { unsigned u; float f; } x; x.u = ((unsigned)s) << 16;
  return x.f;
}
// truncation split: hi = upper 16 bits (1 op vs 4 for RNE). Pair precision
// unchanged: |lo| <= 2^-8|s| (vs 2^-9), lo's RNE error <= 2^-17|s| either way.
__device__ __forceinline__ unsigned short truncbf(float f) {
  union { float f; unsigned u; } x; x.f = f;
  return (unsigned short)(x.u >> 16);
}
__device__ __forceinline__ float bperm(int byteaddr, float v) {
  return __int_as_float(__builtin_amdgcn_ds_bpermute(byteaddr, __float_as_int(v)));
}
// unpack 8 packed u32 (hi16|lo16 per element) -> hi bf16x8 + lo bf16x8.
// Value-verified in R10/R12 (passed correctness); register-only bitcasts.
__device__ __forceinline__ void unpack8(u32x4 a, u32x4 b, bf16x8& H8, bf16x8& L8) {
  union { unsigned u[4]; bf16x8 v; } H, L;
  H.u[0] = (a[1] & 0xFFFF0000u) | (a[0] >> 16);
  H.u[1] = (a[3] & 0xFFFF0000u) | (a[2] >> 16);
  H.u[2] = (b[1] & 0xFFFF0000u) | (b[0] >> 16);
  H.u[3] = (b[3] & 0xFFFF0000u) | (b[2] >> 16);
  L.u[0] = (a[1] << 16) | (a[0] & 0xFFFFu);
  L.u[1] = (a[3] << 16) | (a[2] & 0xFFFFu);
  L.u[2] = (b[1] << 16) | (b[0] & 0xFFFFu);
  L.u[3] = (b[3] << 16) | (b[2] & 0xFFFFu);
  H8 = H.v; L8 = L.v;
}

// ws layout:
//   Qp : u32 [b,v,h,t<300,d] packed (hi16|lo16), 15.36M u32 (old Qh+Ql span)
//   Kh,Kl : ushort [b,v,h,t<300,d] (15.36M each) [K x1/16]
//   Vt : ushort [b,v,h,d][t pad 320] (16,384,000)
//   Oh,Ol : ushort [b,v,t<300,e] (15,360,000 each)
//   WhT,WlT [c][e]; WqTh,WqTl [e][c]; btPad [704][32]
// R14: R13's attn+merge fusion spilled ~500MB/dispatch (oacc[2][4] live across
// the h-loop pushed ~170-reg attn working set past the (256,3) budget; the
// pre-registered WRITE>>20MB tell fired). (256,2) would fit regs but costs a
// resident block (R6: 139->177us) -- expected neutral at best. REVERTED to
// R12-exact, the best verified state (296.3us).
#define QKN 15360000
#define VTN 16384000
#define LOG2E 1.4426950408889634f

// ---------------- prep: transpose/split weights + bf16 bias table ----------------
__global__ __launch_bounds__(256) void prep_kernel(
    const float* __restrict__ w_qkv, const float* __restrict__ w_merge,
    const float* __restrict__ bias_table,
    unsigned short* __restrict__ WqTh, unsigned short* __restrict__ WqTl,
    unsigned short* __restrict__ WhT, unsigned short* __restrict__ WlT,
    unsigned short* __restrict__ btPad)
{
  int i = blockIdx.x * 256 + threadIdx.x;
  if (i < 49152) {                      // w_qkv [c][768] -> [e][c] hi/lo
    int c = i / 768, e = i % 768;
    float v = w_qkv[i];
    unsigned short hb = truncbf(v);
    WqTh[e * 64 + c] = hb; WqTl[e * 64 + c] = f2bf(v - bf2f(hb));
  } else if (i < 65536) {               // w_merge [e][64] -> [c][e] hi/lo
    int j = i - 49152;
    int e = j >> 6, c = j & 63;
    float v = w_merge[j];
    unsigned short hb = truncbf(v);
    WhT[c * EE + e] = hb; WlT[c * EE + e] = f2bf(v - bf2f(hb));
  } else if (i < 65536 + 22528) {       // bias_table -> padded bf16 [704][32]
    int j = i - 65536;
    int row = j >> 5, d = j & 31;
    int g = row - 20;
    float v = (g >= 0 && g < 2 * TT - 1) ? bias_table[g * 32 + d] : 0.f;
    btPad[j] = f2bf(v);
  }
}

// ---------------- Kernel A: QKV projection via MFMA ----------------
// Q stored PACKED u32 (hi16|lo16); K unpacked (attn consumes K in its hot
// loop; R10 showed packed-K unpack there costs +65us). R8 trunc-split + R7
// packed-LDS staging kept.
__global__ __launch_bounds__(256, 3) void qkv_kernel(
    const float* __restrict__ x, const float* __restrict__ b_qkv,
    const unsigned short* __restrict__ WqTh, const unsigned short* __restrict__ WqTl,
    unsigned* __restrict__ Qp,
    unsigned short* __restrict__ Kh, unsigned short* __restrict__ Kl,
    unsigned short* __restrict__ Vt)
{
  __shared__ __align__(16) union {
    unsigned int a[64 * 68];      // sA2[t][c] packed (hi<<16)|lo, stride 68
    unsigned short vtr[256 * 66]; // V transpose buffer [e'][t]
  } sm;

  int blk = blockIdx.x;
  int tt = blk % 5; blk /= 5;
  int v25 = blk % 25; int b = blk / 25;
  int n = b >> 1, m = b & 1;
  int t0 = tt * 60;
  int tid = threadIdx.x;
  int w = tid >> 6, lane = tid & 63, quad = lane >> 4, c16 = lane & 15;

  for (int i = tid; i < 64 * 64; i += 256) {
    int c = i >> 6, t = i & 63;
    float val = 0.f;
    if (t < 60) val = x[((((size_t)n * CC + c) * VV + v25) * TT + (t0 + t)) * MM + m];
    union { float f; unsigned u; } xb; xb.f = val;
    unsigned hi16 = xb.u & 0xFFFF0000u;
    unsigned short lb = f2bf(val - __uint_as_float(hi16));
    sm.a[t * 68 + c] = hi16 | (unsigned)lb;
  }
  __syncthreads();

  bf16x8 ah[4][2], al[4][2];
  #pragma unroll
  for (int mt = 0; mt < 4; ++mt)
    #pragma unroll
    for (int kc = 0; kc < 2; ++kc) {
      const u32x4* p = (const u32x4*)&sm.a[(mt * 16 + c16) * 68 + kc * 32 + quad * 8];
      unpack8(p[0], p[1], ah[mt][kc], al[mt][kc]);
    }
  __syncthreads();  // sA dead; sVt (union) may be written

  size_t bv = (size_t)(b * VV + v25);
  int e0w = w * 192;
  for (int nt = 0; nt < 12; ++nt) {
    int ebase = e0w + nt * 16;
    int e = ebase + c16;
    bf16x8 bh[2], bl[2];
    #pragma unroll
    for (int kc = 0; kc < 2; ++kc) {
      bh[kc] = *(const bf16x8*)&WqTh[(size_t)e * 64 + kc * 32 + quad * 8];
      bl[kc] = *(const bf16x8*)&WqTl[(size_t)e * 64 + kc * 32 + quad * 8];
    }
    f32x4 acc[4];
    #pragma unroll
    for (int mt = 0; mt < 4; ++mt) {
      acc[mt] = (f32x4){0.f, 0.f, 0.f, 0.f};
      #pragma unroll
      for (int kc = 0; kc < 2; ++kc) {
        acc[mt] = __builtin_amdgcn_mfma_f32_16x16x32_bf16(ah[mt][kc], bh[kc], acc[mt], 0, 0, 0);
        acc[mt] = __builtin_amdgcn_mfma_f32_16x16x32_bf16(al[mt][kc], bh[kc], acc[mt], 0, 0, 0);
        acc[mt] = __builtin_amdgcn_mfma_f32_16x16x32_bf16(ah[mt][kc], bl[kc], acc[mt], 0, 0, 0);
      }
    }
    float bias = b_qkv[e];
    int which = ebase >> 8;  // wave-uniform
    if (which == 0) {        // Q: packed u32 store
      int hh = (e >> 5) & 7, dd = e & 31;
      size_t rowb = (bv * HH + hh) * TT;
      #pragma unroll
      for (int mt = 0; mt < 4; ++mt)
        #pragma unroll
        for (int reg = 0; reg < 4; ++reg) {
          int lrow = mt * 16 + quad * 4 + reg;
          // rows >= 60 would RACE with the next tt-block (zero-staged x)
          if (lrow < 60) {
            int t = t0 + lrow;
            float s = (acc[mt][reg] + bias) * LOG2E;
            union { float f; unsigned u; } sb; sb.f = s;
            unsigned hi16 = sb.u & 0xFFFF0000u;
            unsigned short lb2 = f2bf(s - __uint_as_float(hi16));
            Qp[(rowb + t) * HD + dd] = hi16 | (unsigned)lb2;
          }
        }
    } else if (which == 1) { // K: unpacked hi/lo stores
      int hh = (e >> 5) & 7, dd = e & 31;
      size_t rowb = (bv * HH + hh) * TT;
      #pragma unroll
      for (int mt = 0; mt < 4; ++mt)
        #pragma unroll
        for (int reg = 0; reg < 4; ++reg) {
          int lrow = mt * 16 + quad * 4 + reg;
          if (lrow < 60) {
            int t = t0 + lrow;
            float s = (acc[mt][reg] + bias) * 0.0625f;
            unsigned short hb = truncbf(s);
            size_t idx = (rowb + t) * HD + dd;
            Kh[idx] = hb; Kl[idx] = f2bf(s - bf2f(hb));
          }
        }
    } else {
      int ep = e - 512;
      #pragma unroll
      for (int mt = 0; mt < 4; ++mt)
        #pragma unroll
        for (int reg = 0; reg < 4; ++reg)
          sm.vtr[ep * 66 + mt * 16 + quad * 4 + reg] = f2bf(acc[mt][reg] + bias);
    }
  }
  __syncthreads();
  for (int i = tid; i < 256 * 30; i += 256) {
    int ep = i / 30, tc = (i % 30) * 2;
    int e = 512 + ep;
    int hh = (e >> 5) & 7, dd = e & 31;
    size_t idx = ((bv * HH + hh) * HD + dd) * 320 + t0 + tc;
    *(unsigned int*)&Vt[idx] = *(const unsigned int*)&sm.vtr[ep * 66 + tc];
    // Vt rows t in [300,320) stay poison (finite bf16) -> always hit P=0.
  }
}

// ---------------- Kernel B: MFMA attention, 32 rows/wave, packed Q only ----------------
// R12-proven optimum of this structure: (256,3), 2 row-tiles/wave, rolling
// 3-window R pipeline, early-exit garbage waves, Q from packed u32 via two
// bf16x8 loads + once-per-wave unpack.
__global__ __launch_bounds__(256, 3) void attn17_kernel(
    const unsigned* __restrict__ Qp,
    const unsigned short* __restrict__ Kh, const unsigned short* __restrict__ Kl,
    const unsigned short* __restrict__ Vt, const unsigned short* __restrict__ btPad,
    unsigned short* __restrict__ Oh, unsigned short* __restrict__ Ol)
{
  __shared__ __align__(16) unsigned short sPh[2][128 * 72];  // 36,864 B, rows wave-private

  int bid0 = blockIdx.x;
  int bid = (bid0 & 7) * 600 + (bid0 >> 3);   // 4800 % 8 == 0 -> bijective XCD swizzle
  int lt = bid % 3; int rest = bid / 3;
  int h = rest & 7; rest >>= 3;
  int v = rest % 25; int b = rest / 25;
  int l0 = lt * 128;
  int tid = threadIdx.x;
  int w = tid >> 6, lane = tid & 63, quad = lane >> 4, c16 = lane & 15;
  if (l0 + 32 * w >= TT) return;  // fully-garbage wave: no barriers, sPh wave-private
  size_t tbase = ((size_t)(b * VV + v) * HH + h) * TT;
  size_t vbase = ((size_t)(b * VV + v) * HH + h) * HD;

  const unsigned short* Qp16 = (const unsigned short*)Qp;
  bf16x8 qh[2], qlw[2];
  #pragma unroll
  for (int mt = 0; mt < 2; ++mt) {
    size_t qo = (tbase + l0 + w * 32 + mt * 16 + c16) * HD + quad * 8;  // u32 units
    bf16x8 raw0 = *(const bf16x8*)&Qp16[qo * 2];
    bf16x8 raw1 = *(const bf16x8*)&Qp16[qo * 2 + 8];
    union { bf16x8 v; u32x4 u; } A, B;
    A.v = raw0; B.v = raw1;
    unpack8(A.u, B.u, qh[mt], qlw[mt]);
  }

  // rt-invariant bpermute addresses + selects (per reg)
  int srcaddr[4]; bool sel[4];
  #pragma unroll
  for (int reg = 0; reg < 4; ++reg) {
    srcaddr[reg] = 4 * (quad * 16 + ((15 + 4 * quad + reg - c16) & 15));
    sel[reg] = (4 * quad + reg) > c16;   // a==4
  }

  f32x4 accO[2][2];
  #pragma unroll
  for (int mt = 0; mt < 2; ++mt)
    #pragma unroll
    for (int no = 0; no < 2; ++no)
      accO[mt][no] = (f32x4){0.f, 0.f, 0.f, 0.f};
  float psum[2][4] = {{0.f, 0.f, 0.f, 0.f}, {0.f, 0.f, 0.f, 0.f}};

  #pragma unroll
  for (int rt = 0; rt < 5; ++rt) {
    const int r0 = rt * 64;
    unsigned short* myP = &sPh[rt & 1][32 * w * 72];

    // ---- K loads (shared by both row-tiles) + V (prev tile) + 6 bt tiles ----
    const unsigned short* kb = &Kh[(tbase + r0 + c16) * HD + quad * 8];
    const unsigned short* lb = &Kl[(tbase + r0 + c16) * HD + quad * 8];
    bf16x8 khv[4], klv[4];
    #pragma unroll
    for (int nt = 0; nt < 4; ++nt) {
      khv[nt] = *(const bf16x8*)&kb[nt * 16 * HD];
      klv[nt] = *(const bf16x8*)&lb[nt * 16 * HD];
    }
    bf16x8 vv[2][2];
    if (rt > 0) {
      int p0 = r0 - 64;  // previous tile's base
      #pragma unroll
      for (int kc = 0; kc < 2; ++kc)
        #pragma unroll
        for (int no = 0; no < 2; ++no)
          vv[kc][no] = *(const bf16x8*)&Vt[(vbase + no * 16 + c16) * 320 + p0 + kc * 32 + quad * 8];
    }
    // bt6[j]: rows (l0+256+32w-r0) + 16j + c16; row-tile mt uses j = mt+n5, n5=0..4
    const unsigned short* btb = &btPad[(size_t)(l0 + 256 + 32 * w - r0 + c16) * HD + quad * 8];
    bf16x8 bt6[6];
    #pragma unroll
    for (int j = 0; j < 6; ++j) bt6[j] = *(const bf16x8*)&btb[j * 16 * HD];

    // ---- per row-tile: 3-window rolling pipeline ----
    #pragma unroll
    for (int mt = 0; mt < 2; ++mt) {
      float BA[4], BB[4], BC[4] = {0.f, 0.f, 0.f, 0.f};
      {
        f32x4 r = {0.f, 0.f, 0.f, 0.f};
        r = __builtin_amdgcn_mfma_f32_16x16x32_bf16(qh[mt], bt6[mt + 4], r, 0, 0, 0);
        f32x4 r2 = {0.f, 0.f, 0.f, 0.f};
        r2 = __builtin_amdgcn_mfma_f32_16x16x32_bf16(qh[mt], bt6[mt + 3], r2, 0, 0, 0);
        #pragma unroll
        for (int reg = 0; reg < 4; ++reg) BA[reg] = bperm(srcaddr[reg], r[reg]);
        #pragma unroll
        for (int reg = 0; reg < 4; ++reg) BB[reg] = bperm(srcaddr[reg], r2[reg]);
      }
      #pragma unroll
      for (int nt = 0; nt < 4; ++nt) {
        f32x4 sc = {0.f, 0.f, 0.f, 0.f};
        sc = __builtin_amdgcn_mfma_f32_16x16x32_bf16(qh[mt],  khv[nt], sc, 0, 0, 0);
        sc = __builtin_amdgcn_mfma_f32_16x16x32_bf16(qlw[mt], khv[nt], sc, 0, 0, 0);
        sc = __builtin_amdgcn_mfma_f32_16x16x32_bf16(qh[mt],  klv[nt], sc, 0, 0, 0);
        if (nt < 3) {  // prefetch window W(mt+2-nt), consumed at nt+1
          f32x4 r = {0.f, 0.f, 0.f, 0.f};
          r = __builtin_amdgcn_mfma_f32_16x16x32_bf16(qh[mt], bt6[mt + 2 - nt], r, 0, 0, 0);
          #pragma unroll
          for (int reg = 0; reg < 4; ++reg) BC[reg] = bperm(srcaddr[reg], r[reg]);
        }

        bool bad = (r0 + nt * 16 + c16) >= TT;
        #pragma unroll
        for (int reg = 0; reg < 4; ++reg) {
          float ri = sel[reg] ? BA[reg] : BB[reg];
          float p = bad ? 0.f : __builtin_amdgcn_exp2f(sc[reg] + ri);
          psum[mt][reg] += p;
          myP[(mt * 16 + 4 * quad + reg) * 72 + nt * 16 + c16] = f2bf(p);
        }
        #pragma unroll
        for (int reg = 0; reg < 4; ++reg) { BA[reg] = BB[reg]; BB[reg] = BC[reg]; }
      }
    }

    // ---- PV for PREVIOUS tile (buffer (rt-1)&1) ----
    if (rt > 0) {
      unsigned short* prevP = &sPh[(rt - 1) & 1][32 * w * 72];
      #pragma unroll
      for (int mt = 0; mt < 2; ++mt)
        #pragma unroll
        for (int kc = 0; kc < 2; ++kc) {
          bf16x8 pf = *(const bf16x8*)&prevP[(mt * 16 + c16) * 72 + kc * 32 + quad * 8];
          #pragma unroll
          for (int no = 0; no < 2; ++no)
            accO[mt][no] = __builtin_amdgcn_mfma_f32_16x16x32_bf16(pf, vv[kc][no], accO[mt][no], 0, 0, 0);
        }
    }
  }
  // ---- tail PV for rt=4 (buffer 0) ----
  {
    int p0 = 4 * 64;
    unsigned short* prevP = &sPh[0][32 * w * 72];
    #pragma unroll
    for (int kc = 0; kc < 2; ++kc) {
      bf16x8 vfr[2];
      #pragma unroll
      for (int no = 0; no < 2; ++no)
        vfr[no] = *(const bf16x8*)&Vt[(vbase + no * 16 + c16) * 320 + p0 + kc * 32 + quad * 8];
      #pragma unroll
      for (int mt = 0; mt < 2; ++mt) {
        bf16x8 pf = *(const bf16x8*)&prevP[(mt * 16 + c16) * 72 + kc * 32 + quad * 8];
        #pragma unroll
        for (int no = 0; no < 2; ++no)
          accO[mt][no] = __builtin_amdgcn_mfma_f32_16x16x32_bf16(pf, vfr[no], accO[mt][no], 0, 0, 0);
      }
    }
  }

  // ---- row-sum reduce + epilogue ----
  #pragma unroll
  for (int mt = 0; mt < 2; ++mt)
    #pragma unroll
    for (int reg = 0; reg < 4; ++reg) {
      #pragma unroll
      for (int off = 1; off <= 8; off <<= 1)
        psum[mt][reg] += __shfl_xor(psum[mt][reg], off);
    }
  size_t obase = (size_t)(b * VV + v) * TT;
  #pragma unroll
  for (int mt = 0; mt < 2; ++mt)
    #pragma unroll
    for (int no = 0; no < 2; ++no)
      #pragma unroll
      for (int reg = 0; reg < 4; ++reg) {
        int gl = l0 + 32 * w + 16 * mt + 4 * quad + reg;
        if (gl < TT) {
          float o = accO[mt][no][reg] / psum[mt][reg];
          size_t oi = (obase + gl) * EE + h * HD + no * 16 + c16;
          unsigned short hb = truncbf(o);
          Oh[oi] = hb; Ol[oi] = f2bf(o - bf2f(hb));
        }
      }
}

// ---------------- Kernel C: merge projection, m-fused, 1000 blocks (R8) ----------------
__global__ __launch_bounds__(256, 4) void merge4_kernel(
    const unsigned short* __restrict__ Oh, const unsigned short* __restrict__ Ol,
    const unsigned short* __restrict__ WhT, const unsigned short* __restrict__ WlT,
    const float* __restrict__ b_merge, float* __restrict__ out)
{
  int blk = blockIdx.x;
  int tt = blk % 10; blk /= 10;
  int v = blk % 25; int nb = blk / 25;   // nb in [0,4)
  int tid = threadIdx.x;
  int w = tid >> 6, lane = tid & 63, quad = lane >> 4, c16 = lane & 15;
  int t0 = tt * 30;
  int cidx = w * 16 + c16;
  size_t obase0 = ((size_t)(nb * 2 + 0) * VV + v) * TT;
  size_t obase1 = ((size_t)(nb * 2 + 1) * VV + v) * TT;

  f32x4 acc[2][2];  // [mm][mt]
  #pragma unroll
  for (int mm = 0; mm < 2; ++mm)
    #pragma unroll
    for (int mt = 0; mt < 2; ++mt)
      acc[mm][mt] = (f32x4){0.f, 0.f, 0.f, 0.f};

  for (int ks = 0; ks < 8; ++ks) {
    int eoff = ks * 32 + quad * 8;
    bf16x8 bh = *(const bf16x8*)&WhT[(size_t)cidx * EE + eoff];
    bf16x8 bl = *(const bf16x8*)&WlT[(size_t)cidx * EE + eoff];
    #pragma unroll
    for (int mm = 0; mm < 2; ++mm) {
      size_t ob = (mm == 0) ? obase0 : obase1;
      #pragma unroll
      for (int mt = 0; mt < 2; ++mt) {
        size_t ao = (ob + t0 + mt * 16 + c16) * EE + eoff;
        bf16x8 ahv = *(const bf16x8*)&Oh[ao];
        bf16x8 alv = *(const bf16x8*)&Ol[ao];
        acc[mm][mt] = __builtin_amdgcn_mfma_f32_16x16x32_bf16(ahv, bh, acc[mm][mt], 0, 0, 0);
        acc[mm][mt] = __builtin_amdgcn_mfma_f32_16x16x32_bf16(alv, bh, acc[mm][mt], 0, 0, 0);
        acc[mm][mt] = __builtin_amdgcn_mfma_f32_16x16x32_bf16(ahv, bl, acc[mm][mt], 0, 0, 0);
      }
    }
  }
  float bm = b_merge[cidx];
  size_t rowbase = ((size_t)nb * CC + cidx) * VV + v;  // out row for (nb, cidx, v)
  #pragma unroll
  for (int mt = 0; mt < 2; ++mt)
    #pragma unroll
    for (int reg = 0; reg < 4; ++reg) {
      int lrow = mt * 16 + 4 * quad + reg;
      if (lrow < 30) {
        int t = t0 + lrow;
        f32x2 pr;
        pr[0] = acc[0][mt][reg] + bm;
        pr[1] = acc[1][mt][reg] + bm;
        *(f32x2*)&out[rowbase * TT * MM + (size_t)t * MM] = pr;
      }
    }
}

extern "C" void kernel_launch(void* const* d_in, const int* in_sizes, int n_in,
                              void* d_out, int out_size, void* d_ws, size_t ws_size,
                              hipStream_t stream) {
  const float* x          = (const float*)d_in[0];
  const float* w_qkv      = (const float*)d_in[1];
  const float* b_qkv      = (const float*)d_in[2];
  const float* w_merge    = (const float*)d_in[3];
  const float* b_merge    = (const float*)d_in[4];
  const float* bias_table = (const float*)d_in[5];
  float* out = (float*)d_out;
  unsigned short* ws16 = (unsigned short*)d_ws;
  unsigned* Qp = (unsigned*)ws16;                          // 15.36M u32 (old Qh+Ql span)
  unsigned short* Kh   = ws16 + (size_t)2 * QKN;
  unsigned short* Kl   = ws16 + (size_t)3 * QKN;
  unsigned short* Vt   = ws16 + (size_t)4 * QKN;
  unsigned short* Oh   = ws16 + (size_t)4 * QKN + VTN;
  unsigned short* Ol   = ws16 + (size_t)5 * QKN + VTN;
  unsigned short* base8 = ws16 + (size_t)6 * QKN + VTN;
  unsigned short* WhT  = base8;
  unsigned short* WlT  = base8 + 16384;
  unsigned short* WqTh = base8 + 32768;
  unsigned short* WqTl = base8 + 81920;
  unsigned short* btPad = base8 + 131072;

  prep_kernel<<<dim3(344), dim3(256), 0, stream>>>(w_qkv, w_merge, bias_table,
                                                   WqTh, WqTl, WhT, WlT, btPad);
  qkv_kernel<<<dim3(1000), dim3(256), 0, stream>>>(x, b_qkv, WqTh, WqTl,
                                                   Qp, Kh, Kl, Vt);
  attn17_kernel<<<dim3(4800), dim3(256), 0, stream>>>(Qp, Kh, Kl, Vt, btPad, Oh, Ol);
  merge4_kernel<<<dim3(1000), dim3(256), 0, stream>>>(Oh, Ol, WhT, WlT, b_merge, out);
}